// Round 6
// baseline (522.173 us; speedup 1.0000x reference)
//
#include <hip/hip_runtime.h>
#include <math.h>

#define N_NODES 50000
#define N_EDGES 800000
#define E_TOT   850000
#define F_IN    256
#define F1      512
#define HID     128
#define HEADS   4
#define F_OUT   64

typedef __attribute__((ext_vector_type(8))) short short8;
typedef __attribute__((ext_vector_type(4))) float f32x4;
typedef unsigned short ushort_t;
typedef unsigned int uint_t;

__device__ __forceinline__ float lrelu(float x){ return x > 0.f ? x : 0.2f*x; }
__device__ __forceinline__ float elu(float x){ return x > 0.f ? x : expm1f(x); }

__device__ __forceinline__ ushort_t f2b(float f){
  uint_t u = __builtin_bit_cast(uint_t, f);
  u += 0x7fffu + ((u >> 16) & 1u);
  return (ushort_t)(u >> 16);
}
__device__ __forceinline__ float blo(uint_t u){ return __builtin_bit_cast(float, u << 16); }
__device__ __forceinline__ float bhi(uint_t u){ return __builtin_bit_cast(float, u & 0xffff0000u); }
__device__ __forceinline__ float b2f(ushort_t s){ return __builtin_bit_cast(float, (uint_t)s << 16); }

// split fp32 -> hi/lo bf16 (hi rounded-to-nearest, lo = residual; combined ~2^-17 rel)
__device__ __forceinline__ void fsplit(float v, ushort_t& hi, ushort_t& lo){
  hi = f2b(v);
  lo = f2b(v - b2f(hi));
}

__device__ __forceinline__ void gld_lds16(const void* g, void* l){
  __builtin_amdgcn_global_load_lds((const __attribute__((address_space(1))) unsigned int*)g,
                                   (__attribute__((address_space(3))) unsigned int*)l, 16, 0, 0);
}

// ---------------- CSR build ----------------
__global__ void hist_kernel(const int* __restrict__ ei, int* __restrict__ deg){
  int e = blockIdx.x*blockDim.x + threadIdx.x;
  if (e >= E_TOT) return;
  int dst = (e < N_EDGES) ? ei[N_EDGES + e] : (e - N_EDGES);
  atomicAdd(&deg[dst], 1);
}

__global__ __launch_bounds__(256) void scan1_kernel(const int* __restrict__ deg,
                                                    int* __restrict__ offs,
                                                    int* __restrict__ bsum){
  __shared__ int sd[256];
  const int tid = threadIdx.x;
  const int i = blockIdx.x*256 + tid;
  int v = (i < N_NODES) ? deg[i] : 0;
  sd[tid] = v; __syncthreads();
  #pragma unroll
  for (int off = 1; off < 256; off <<= 1){
    int t = (tid >= off) ? sd[tid - off] : 0;
    __syncthreads();
    sd[tid] += t;
    __syncthreads();
  }
  if (i < N_NODES) offs[i] = sd[tid] - v;
  if (tid == 255) bsum[blockIdx.x] = sd[255];
}

__global__ __launch_bounds__(256) void scan2_kernel(const int* __restrict__ bsum,
                                                    int* __restrict__ bbase, int nb){
  __shared__ int sd[256];
  const int tid = threadIdx.x;
  int v = (tid < nb) ? bsum[tid] : 0;
  sd[tid] = v; __syncthreads();
  #pragma unroll
  for (int off = 1; off < 256; off <<= 1){
    int t = (tid >= off) ? sd[tid - off] : 0;
    __syncthreads();
    sd[tid] += t;
    __syncthreads();
  }
  if (tid < nb) bbase[tid] = sd[tid] - v;
}

__global__ __launch_bounds__(256) void scan3_kernel(int* __restrict__ offs,
                                                    const int* __restrict__ bbase,
                                                    int* __restrict__ cur){
  const int i = blockIdx.x*256 + threadIdx.x;
  if (i < N_NODES){
    int o = offs[i] + bbase[blockIdx.x];
    offs[i] = o;
    cur[i] = o;
  }
  if (blockIdx.x == 0 && threadIdx.x == 0) offs[N_NODES] = E_TOT;
}

__global__ void scatter_kernel(const int* __restrict__ ei, int* __restrict__ cur,
                               int* __restrict__ ssrc){
  int e = blockIdx.x*blockDim.x + threadIdx.x;
  if (e >= E_TOT) return;
  int src, dst;
  if (e < N_EDGES){ src = ei[e]; dst = ei[N_EDGES + e]; }
  else            { src = e - N_EDGES; dst = src; }
  int pos = atomicAdd(&cur[dst], 1);
  ssrc[pos] = src;
}

// Deterministic bucket order: race-free in-register odd-even sort via shfl.
__global__ __launch_bounds__(256) void sort_kernel(const int* __restrict__ offs,
                                                   int* __restrict__ ssrc){
  const int wave = threadIdx.x >> 6, lane = threadIdx.x & 63;
  const int n = blockIdx.x*4 + wave;
  const int s0 = offs[n];
  const int len = offs[n+1] - s0;
  if (len <= 1) return;
  if (len <= 64){
    int v = (lane < len) ? ssrc[s0 + lane] : 0x7fffffff;
    for (int p = 0; p < len; ++p){
      const int left = ((lane & 1) == (p & 1));
      const int partner = left ? lane + 1 : lane - 1;
      const int pv = __shfl(v, partner & 63);
      const int nv = left ? min(v, pv) : max(v, pv);
      v = (partner >= 0 && partner < 64) ? nv : v;
    }
    if (lane < len) ssrc[s0 + lane] = v;
  } else if (lane == 0){
    for (int i = 1; i < len; ++i){
      int v = ssrc[s0 + i]; int j = i - 1;
      while (j >= 0 && ssrc[s0 + j] > v){ ssrc[s0 + j + 1] = ssrc[s0 + j]; --j; }
      ssrc[s0 + j + 1] = v;
    }
  }
}

// ---------------- prep: fp32 -> bf16 hi/lo split ----------------
__global__ __launch_bounds__(256) void cvt_x_split_kernel(const float* __restrict__ x,
                                                          ushort_t* __restrict__ xh,
                                                          ushort_t* __restrict__ xl){
  const int t = blockIdx.x*256 + threadIdx.x;
  const float4 a = ((const float4*)x)[t*2];
  const float4 b = ((const float4*)x)[t*2 + 1];
  float v[8] = {a.x,a.y,a.z,a.w,b.x,b.y,b.z,b.w};
  ushort_t h[8], l[8];
  #pragma unroll
  for (int i = 0; i < 8; ++i) fsplit(v[i], h[i], l[i]);
  uint4 oh, ol;
  oh.x = (uint_t)h[0] | ((uint_t)h[1] << 16);
  oh.y = (uint_t)h[2] | ((uint_t)h[3] << 16);
  oh.z = (uint_t)h[4] | ((uint_t)h[5] << 16);
  oh.w = (uint_t)h[6] | ((uint_t)h[7] << 16);
  ol.x = (uint_t)l[0] | ((uint_t)l[1] << 16);
  ol.y = (uint_t)l[2] | ((uint_t)l[3] << 16);
  ol.z = (uint_t)l[4] | ((uint_t)l[5] << 16);
  ol.w = (uint_t)l[6] | ((uint_t)l[7] << 16);
  ((uint4*)xh)[t] = oh;
  ((uint4*)xl)[t] = ol;
}

// W [K][N] fp32 -> Wt hi/lo [N][K] bf16
__global__ __launch_bounds__(256) void transpose_split_kernel(const float* __restrict__ W,
                                                              ushort_t* __restrict__ Wth,
                                                              ushort_t* __restrict__ Wtl,
                                                              int K, int N){
  __shared__ float tile[64][65];
  const int k0 = blockIdx.x*64, n0 = blockIdx.y*64;
  const int c = threadIdx.x & 63, r4 = threadIdx.x >> 6;
  for (int r = r4; r < 64; r += 4)
    tile[r][c] = W[(size_t)(k0 + r)*N + n0 + c];
  __syncthreads();
  for (int r = r4; r < 64; r += 4){
    ushort_t hi, lo;
    fsplit(tile[c][r], hi, lo);
    Wth[(size_t)(n0 + r)*K + k0 + c] = hi;
    Wtl[(size_t)(n0 + r)*K + k0 + c] = lo;
  }
}

// ---------------- bf16x3 MFMA GEMM + fused attention logits ----------------
template<int K, int BM, int BN, int WR, int WC, int NH, int CH, bool CF32>
__global__ __launch_bounds__(256) void gemm_x3(const ushort_t* __restrict__ Ah,
                                               const ushort_t* __restrict__ Al,
                                               const ushort_t* __restrict__ Bh,
                                               const ushort_t* __restrict__ Bl,
                                               void* __restrict__ Cout,
                                               const float* __restrict__ a_src,
                                               const float* __restrict__ a_dst,
                                               float* __restrict__ als,
                                               float* __restrict__ ald,
                                               int M){
  constexpr int NTOT = NH*CH;
  __shared__ ushort_t Ash[BM*32], Asl[BM*32];
  __shared__ ushort_t Bsh[BN*32], Bsl[BN*32];
  __shared__ float slog[WC][BM][2];
  const int tid = threadIdx.x;
  const int wave = tid >> 6, lane = tid & 63, quad = lane >> 4, l16 = lane & 15;
  const int wm = wave % WR, wn = wave / WR;
  const int m0 = blockIdx.x*BM;
  const int head = blockIdx.y;
  const int n0 = head*BN;
  f32x4 acc[4][4] = {};
  for (int k0 = 0; k0 < K; k0 += 32){
    for (int idx = tid; idx < BM*4; idx += 256){
      int row = idx >> 2, ch = idx & 3;
      int gr = m0 + row; gr = (gr < M) ? gr : (M - 1);
      gld_lds16(Ah + (size_t)gr*K + k0 + ch*8, (char*)Ash + idx*16);
      gld_lds16(Al + (size_t)gr*K + k0 + ch*8, (char*)Asl + idx*16);
    }
    for (int idx = tid; idx < BN*4; idx += 256){
      int row = idx >> 2, ch = idx & 3;
      gld_lds16(Bh + (size_t)(n0 + row)*K + k0 + ch*8, (char*)Bsh + idx*16);
      gld_lds16(Bl + (size_t)(n0 + row)*K + k0 + ch*8, (char*)Bsl + idx*16);
    }
    __syncthreads();
    short8 afh[4], afl[4], bfh[4], bfl[4];
    #pragma unroll
    for (int i = 0; i < 4; ++i){
      afh[i] = *(const short8*)(Ash + (wm*64 + i*16 + l16)*32 + quad*8);
      afl[i] = *(const short8*)(Asl + (wm*64 + i*16 + l16)*32 + quad*8);
    }
    #pragma unroll
    for (int j = 0; j < 4; ++j){
      bfh[j] = *(const short8*)(Bsh + (wn*64 + j*16 + l16)*32 + quad*8);
      bfl[j] = *(const short8*)(Bsl + (wn*64 + j*16 + l16)*32 + quad*8);
    }
    #pragma unroll
    for (int i = 0; i < 4; ++i)
      #pragma unroll
      for (int j = 0; j < 4; ++j){
        acc[i][j] = __builtin_amdgcn_mfma_f32_16x16x32_bf16(afh[i], bfh[j], acc[i][j], 0, 0, 0);
        acc[i][j] = __builtin_amdgcn_mfma_f32_16x16x32_bf16(afl[i], bfh[j], acc[i][j], 0, 0, 0);
        acc[i][j] = __builtin_amdgcn_mfma_f32_16x16x32_bf16(afh[i], bfl[j], acc[i][j], 0, 0, 0);
      }
    __syncthreads();
  }
  // C store
  #pragma unroll
  for (int i = 0; i < 4; ++i){
    #pragma unroll
    for (int r = 0; r < 4; ++r){
      int row = m0 + wm*64 + i*16 + quad*4 + r;
      if (row < M){
        #pragma unroll
        for (int j = 0; j < 4; ++j){
          int col = n0 + wn*64 + j*16 + l16;
          if (CF32) ((float*)Cout)[(size_t)row*NTOT + col] = acc[i][j][r];
          else      ((ushort_t*)Cout)[(size_t)row*NTOT + col] = f2b(acc[i][j][r]);
        }
      }
    }
  }
  // fused logits
  float aws[4], awd[4];
  #pragma unroll
  for (int j = 0; j < 4; ++j){
    int cih = wn*64 + j*16 + l16;
    aws[j] = a_src[head*CH + cih];
    awd[j] = a_dst[head*CH + cih];
  }
  #pragma unroll
  for (int i = 0; i < 4; ++i){
    #pragma unroll
    for (int r = 0; r < 4; ++r){
      float s = acc[i][0][r]*aws[0] + acc[i][1][r]*aws[1]
              + acc[i][2][r]*aws[2] + acc[i][3][r]*aws[3];
      float d = acc[i][0][r]*awd[0] + acc[i][1][r]*awd[1]
              + acc[i][2][r]*awd[2] + acc[i][3][r]*awd[3];
      #pragma unroll
      for (int off = 8; off >= 1; off >>= 1){
        s += __shfl_xor(s, off);
        d += __shfl_xor(d, off);
      }
      if (l16 == 0){
        slog[wn][wm*64 + i*16 + quad*4 + r][0] = s;
        slog[wn][wm*64 + i*16 + quad*4 + r][1] = d;
      }
    }
  }
  __syncthreads();
  for (int t = tid; t < BM; t += 256){
    float s = slog[0][t][0], d = slog[0][t][1];
    if (WC > 1){ s += slog[WC-1][t][0]; d += slog[WC-1][t][1]; }
    int row = m0 + t;
    if (row < M){
      als[row*NH + head] = s;
      ald[row*NH + head] = d;
    }
  }
}

#define FMA8(hv, al)                              \
  acc[0] = fmaf(blo((hv).x), (al), acc[0]);       \
  acc[1] = fmaf(bhi((hv).x), (al), acc[1]);       \
  acc[2] = fmaf(blo((hv).y), (al), acc[2]);       \
  acc[3] = fmaf(bhi((hv).y), (al), acc[3]);       \
  acc[4] = fmaf(blo((hv).z), (al), acc[4]);       \
  acc[5] = fmaf(bhi((hv).z), (al), acc[5]);       \
  acc[6] = fmaf(blo((hv).w), (al), acc[6]);       \
  acc[7] = fmaf(bhi((hv).w), (al), acc[7]);

// ---------------- layer-1 aggregation (wave per dst, 4-deep MLP) ------------
__global__ __launch_bounds__(256) void agg1_kernel(const ushort_t* __restrict__ h1b,
                                                   const float* __restrict__ als,
                                                   const float* __restrict__ ald1,
                                                   const float* __restrict__ b1,
                                                   const int* __restrict__ offs,
                                                   const int* __restrict__ ssrc,
                                                   ushort_t* __restrict__ hbh,
                                                   ushort_t* __restrict__ hbl){
  __shared__ int   shsrc[4][64];
  __shared__ float shal[4][64][4];
  const int wave = threadIdx.x >> 6, lane = threadIdx.x & 63;
  const int n = blockIdx.x*4 + wave;
  const int head = lane >> 4;
  const float4 ald = ((const float4*)ald1)[n];
  const int s0 = offs[n], s1 = offs[n+1];

  // pass 1: softmax denominators
  float d0 = 0.f, d1 = 0.f, d2 = 0.f, d3 = 0.f;
  for (int e = s0 + lane; e < s1; e += 64){
    const int sc = ssrc[e];
    const float4 as = ((const float4*)als)[sc];
    d0 += __expf(lrelu(as.x + ald.x));
    d1 += __expf(lrelu(as.y + ald.y));
    d2 += __expf(lrelu(as.z + ald.z));
    d3 += __expf(lrelu(as.w + ald.w));
  }
  #pragma unroll
  for (int off = 32; off >= 1; off >>= 1){
    d0 += __shfl_xor(d0, off);
    d1 += __shfl_xor(d1, off);
    d2 += __shfl_xor(d2, off);
    d3 += __shfl_xor(d3, off);
  }
  const float rd0 = 1.0f/(d0 + 1e-16f), rd1 = 1.0f/(d1 + 1e-16f);
  const float rd2 = 1.0f/(d2 + 1e-16f), rd3 = 1.0f/(d3 + 1e-16f);

  // pass 2: weighted aggregation; lane covers feats lane*8..+7 (head = lane>>4)
  float acc[8] = {0.f,0.f,0.f,0.f,0.f,0.f,0.f,0.f};
  for (int ce = s0; ce < s1; ce += 64){
    const int idx = ce + lane;
    if (idx < s1){
      const int sc = ssrc[idx];
      const float4 as = ((const float4*)als)[sc];
      shsrc[wave][lane] = sc;
      float4 a4;
      a4.x = __expf(lrelu(as.x + ald.x)) * rd0;
      a4.y = __expf(lrelu(as.y + ald.y)) * rd1;
      a4.z = __expf(lrelu(as.z + ald.z)) * rd2;
      a4.w = __expf(lrelu(as.w + ald.w)) * rd3;
      *(float4*)&shal[wave][lane][0] = a4;
    }
    __builtin_amdgcn_wave_barrier();      // stop compiler reordering LDS W->R
    const int nE = min(64, s1 - ce);
    int k = 0;
    // 4-deep: hoist 4 independent loads, then FMA in ascending edge order
    // (identical fp32 summation order to the 1-deep loop).
    for (; k + 4 <= nE; k += 4){
      const int sA = shsrc[wave][k+0], sB = shsrc[wave][k+1];
      const int sC = shsrc[wave][k+2], sD = shsrc[wave][k+3];
      const float aA = shal[wave][k+0][head], aB = shal[wave][k+1][head];
      const float aC = shal[wave][k+2][head], aD = shal[wave][k+3][head];
      const uint4 hA = *(const uint4*)(h1b + (size_t)sA*F1 + lane*8);
      const uint4 hB = *(const uint4*)(h1b + (size_t)sB*F1 + lane*8);
      const uint4 hC = *(const uint4*)(h1b + (size_t)sC*F1 + lane*8);
      const uint4 hD = *(const uint4*)(h1b + (size_t)sD*F1 + lane*8);
      FMA8(hA, aA); FMA8(hB, aB); FMA8(hC, aC); FMA8(hD, aD);
    }
    for (; k < nE; ++k){
      const int sA = shsrc[wave][k];
      const float aA = shal[wave][k][head];
      const uint4 hA = *(const uint4*)(h1b + (size_t)sA*F1 + lane*8);
      FMA8(hA, aA);
    }
    __builtin_amdgcn_wave_barrier();
  }
  const float4 ba = *(const float4*)(b1 + lane*8);
  const float4 bb = *(const float4*)(b1 + lane*8 + 4);
  float o[8];
  o[0] = elu(acc[0] + ba.x); o[1] = elu(acc[1] + ba.y);
  o[2] = elu(acc[2] + ba.z); o[3] = elu(acc[3] + ba.w);
  o[4] = elu(acc[4] + bb.x); o[5] = elu(acc[5] + bb.y);
  o[6] = elu(acc[6] + bb.z); o[7] = elu(acc[7] + bb.w);
  ushort_t h[8], l[8];
  #pragma unroll
  for (int i = 0; i < 8; ++i) fsplit(o[i], h[i], l[i]);
  uint4 oh, ol;
  oh.x = (uint_t)h[0] | ((uint_t)h[1] << 16);
  oh.y = (uint_t)h[2] | ((uint_t)h[3] << 16);
  oh.z = (uint_t)h[4] | ((uint_t)h[5] << 16);
  oh.w = (uint_t)h[6] | ((uint_t)h[7] << 16);
  ol.x = (uint_t)l[0] | ((uint_t)l[1] << 16);
  ol.y = (uint_t)l[2] | ((uint_t)l[3] << 16);
  ol.z = (uint_t)l[4] | ((uint_t)l[5] << 16);
  ol.w = (uint_t)l[6] | ((uint_t)l[7] << 16);
  *(uint4*)(hbh + (size_t)n*F1 + lane*8) = oh;
  *(uint4*)(hbl + (size_t)n*F1 + lane*8) = ol;
}

// ---------------- layer-2 aggregation (wave per dst, fp32 gather) ----------
__global__ __launch_bounds__(256) void agg2_kernel(const float* __restrict__ gb,
                                                   const float* __restrict__ als,
                                                   const float* __restrict__ ald2,
                                                   const float* __restrict__ b2,
                                                   const int* __restrict__ offs,
                                                   const int* __restrict__ ssrc,
                                                   float* __restrict__ out){
  __shared__ int   shsrc[4][64];
  __shared__ float shal[4][64];
  const int wave = threadIdx.x >> 6, lane = threadIdx.x & 63;
  const int n = blockIdx.x*4 + wave;
  const int g = lane >> 4, l16 = lane & 15;
  const float ald = ald2[n];
  const int s0 = offs[n], s1 = offs[n+1];

  float dsum = 0.f;
  for (int e = s0 + lane; e < s1; e += 64)
    dsum += __expf(lrelu(als[ssrc[e]] + ald));
  #pragma unroll
  for (int off = 32; off >= 1; off >>= 1)
    dsum += __shfl_xor(dsum, off);
  const float rd = 1.0f / (dsum + 1e-16f);

  float a0 = 0.f, a1 = 0.f, a2 = 0.f, a3 = 0.f;
  for (int ce = s0; ce < s1; ce += 64){
    const int idx = ce + lane;
    if (idx < s1){
      const int sc = ssrc[idx];
      shsrc[wave][lane] = sc;
      shal[wave][lane] = __expf(lrelu(als[sc] + ald)) * rd;
    }
    __builtin_amdgcn_wave_barrier();
    const int nE = min(64, s1 - ce);
    // 2-deep unroll; each lane-group's accumulation order unchanged.
    int k = 0;
    for (; k + 8 <= nE; k += 8){
      const int eA = k + g, eB = k + 4 + g;
      const int sA = shsrc[wave][eA], sB = shsrc[wave][eB];
      const float aA = shal[wave][eA], aB = shal[wave][eB];
      const float4 hA = *(const float4*)(gb + (size_t)sA*F_OUT + l16*4);
      const float4 hB = *(const float4*)(gb + (size_t)sB*F_OUT + l16*4);
      a0 = fmaf(hA.x, aA, a0); a1 = fmaf(hA.y, aA, a1);
      a2 = fmaf(hA.z, aA, a2); a3 = fmaf(hA.w, aA, a3);
      a0 = fmaf(hB.x, aB, a0); a1 = fmaf(hB.y, aB, a1);
      a2 = fmaf(hB.z, aB, a2); a3 = fmaf(hB.w, aB, a3);
    }
    for (; k < nE; k += 4){
      const int e = k + g;
      float al = 0.f;
      int sc = shsrc[wave][0];
      if (e < nE){ sc = shsrc[wave][e]; al = shal[wave][e]; }
      const float4 hv = *(const float4*)(gb + (size_t)sc*F_OUT + l16*4);
      a0 = fmaf(hv.x, al, a0); a1 = fmaf(hv.y, al, a1);
      a2 = fmaf(hv.z, al, a2); a3 = fmaf(hv.w, al, a3);
    }
    __builtin_amdgcn_wave_barrier();
  }
  a0 += __shfl_xor(a0, 16); a0 += __shfl_xor(a0, 32);
  a1 += __shfl_xor(a1, 16); a1 += __shfl_xor(a1, 32);
  a2 += __shfl_xor(a2, 16); a2 += __shfl_xor(a2, 32);
  a3 += __shfl_xor(a3, 16); a3 += __shfl_xor(a3, 32);
  if (g == 0){
    const float4 bv = *(const float4*)(b2 + l16*4);
    float4 o = {a0 + bv.x, a1 + bv.y, a2 + bv.z, a3 + bv.w};
    *(float4*)(out + (size_t)n*F_OUT + l16*4) = o;
  }
}

extern "C" void kernel_launch(void* const* d_in, const int* in_sizes, int n_in,
                              void* d_out, int out_size, void* d_ws, size_t ws_size,
                              hipStream_t stream){
  const float* x      = (const float*)d_in[0];
  const int*   ei     = (const int*)  d_in[1];
  const float* W1     = (const float*)d_in[2];
  const float* a_src1 = (const float*)d_in[3];
  const float* a_dst1 = (const float*)d_in[4];
  const float* b1     = (const float*)d_in[5];
  const float* W2     = (const float*)d_in[6];
  const float* a_src2 = (const float*)d_in[7];
  const float* a_dst2 = (const float*)d_in[8];
  const float* b2     = (const float*)d_in[9];
  float* out = (float*)d_out;

  char* ws = (char*)d_ws;
  ushort_t* xh   = (ushort_t*)(ws + 0UL);            // [N,256] bf16 = 25.6 MB
  ushort_t* xl   = (ushort_t*)(ws + 25600000UL);     // [N,256] bf16 = 25.6 MB
  ushort_t* hbh  = (ushort_t*)(ws + 0UL);            // [N,512] bf16 = 51.2 MB (reuse)
  ushort_t* h1b  = (ushort_t*)(ws + 51200000UL);     // [N,512] bf16 = 51.2 MB
  ushort_t* hbl  = (ushort_t*)(ws + 102400000UL);    // [N,512] bf16 = 51.2 MB
  float*    gb   = (float*)   (ws + 153600000UL);    // [N,64] fp32 = 12.8 MB
  ushort_t* W1th = (ushort_t*)(ws + 166400000UL);    // [512][256] bf16
  ushort_t* W1tl = (ushort_t*)(ws + 166662144UL);
  ushort_t* W2th = (ushort_t*)(ws + 166924288UL);    // [64][512] bf16
  ushort_t* W2tl = (ushort_t*)(ws + 166989824UL);
  float*    als1 = (float*)   (ws + 167055360UL);    // [N,4]
  float*    ald1 = (float*)   (ws + 167855360UL);    // [N,4]
  float*    als2 = (float*)   (ws + 168655360UL);    // [N]
  float*    ald2 = (float*)   (ws + 168855360UL);    // [N]
  int*      deg  = (int*)     (ws + 169055360UL);    // [N]
  int*      offs = (int*)     (ws + 169255360UL);    // [N+1]
  int*      bsum = (int*)     (ws + 169455616UL);    // [196]
  int*      bbase= (int*)     (ws + 169456640UL);    // [196]
  int*      cur  = (int*)     (ws + 169457664UL);    // [N]
  int*      ssrc = (int*)     (ws + 169657664UL);    // [E_TOT]

  hipMemsetAsync(deg, 0, 200000, stream);

  const int eb = (E_TOT + 255) / 256;
  const int nb = (N_NODES + 255) / 256;              // 196
  hist_kernel   <<<eb, 256, 0, stream>>>(ei, deg);
  scan1_kernel  <<<nb, 256, 0, stream>>>(deg, offs, bsum);
  scan2_kernel  <<<1, 256, 0, stream>>>(bsum, bbase, nb);
  scan3_kernel  <<<nb, 256, 0, stream>>>(offs, bbase, cur);
  scatter_kernel<<<eb, 256, 0, stream>>>(ei, cur, ssrc);
  sort_kernel   <<<12500, 256, 0, stream>>>(offs, ssrc);   // deterministic order

  cvt_x_split_kernel   <<<6250, 256, 0, stream>>>(x, xh, xl);
  transpose_split_kernel<<<dim3(4, 8), 256, 0, stream>>>(W1, W1th, W1tl, F_IN, F1);
  transpose_split_kernel<<<dim3(8, 1), 256, 0, stream>>>(W2, W2th, W2tl, F1, F_OUT);

  // layer 1: bf16x3 gemm + fused logits; grid.y = head
  gemm_x3<F_IN, 128, 128, 2, 2, 4, 128, false>
    <<<dim3(391, 4), 256, 0, stream>>>(xh, xl, W1th, W1tl, h1b,
                                       a_src1, a_dst1, als1, ald1, N_NODES);
  agg1_kernel<<<12500, 256, 0, stream>>>(h1b, als1, ald1, b1, offs, ssrc, hbh, hbl);

  // layer 2: bf16x3 gemm + fused logits (1 head), fp32 C
  gemm_x3<F1, 256, 64, 4, 1, 1, 64, true>
    <<<dim3(196, 1), 256, 0, stream>>>(hbh, hbl, W2th, W2tl, gb,
                                       a_src2, a_dst2, als2, ald2, N_NODES);
  agg2_kernel<<<12500, 256, 0, stream>>>(gb, als2, ald2, b2, offs, ssrc, out);
}

// Round 7
// 473.126 us; speedup vs baseline: 1.1037x; 1.1037x over previous
//
#include <hip/hip_runtime.h>
#include <math.h>

#define N_NODES 50000
#define N_EDGES 800000
#define E_TOT   850000
#define F_IN    256
#define F1      512
#define HID     128
#define HEADS   4
#define F_OUT   64

typedef __attribute__((ext_vector_type(8))) short short8;
typedef __attribute__((ext_vector_type(4))) float f32x4;
typedef unsigned short ushort_t;
typedef unsigned int uint_t;

__device__ __forceinline__ float lrelu(float x){ return x > 0.f ? x : 0.2f*x; }
__device__ __forceinline__ float elu(float x){ return x > 0.f ? x : expm1f(x); }

__device__ __forceinline__ ushort_t f2b(float f){
  uint_t u = __builtin_bit_cast(uint_t, f);
  u += 0x7fffu + ((u >> 16) & 1u);
  return (ushort_t)(u >> 16);
}
__device__ __forceinline__ float blo(uint_t u){ return __builtin_bit_cast(float, u << 16); }
__device__ __forceinline__ float bhi(uint_t u){ return __builtin_bit_cast(float, u & 0xffff0000u); }

__device__ __forceinline__ void gld_lds16(const void* g, void* l){
  __builtin_amdgcn_global_load_lds((const __attribute__((address_space(1))) unsigned int*)g,
                                   (__attribute__((address_space(3))) unsigned int*)l, 16, 0, 0);
}

// ---------------- CSR build ----------------
__global__ void hist_kernel(const int* __restrict__ ei, int* __restrict__ deg){
  int e = blockIdx.x*blockDim.x + threadIdx.x;
  if (e >= E_TOT) return;
  int dst = (e < N_EDGES) ? ei[N_EDGES + e] : (e - N_EDGES);
  atomicAdd(&deg[dst], 1);
}

__global__ __launch_bounds__(256) void scan1_kernel(const int* __restrict__ deg,
                                                    int* __restrict__ offs,
                                                    int* __restrict__ bsum){
  __shared__ int sd[256];
  const int tid = threadIdx.x;
  const int i = blockIdx.x*256 + tid;
  int v = (i < N_NODES) ? deg[i] : 0;
  sd[tid] = v; __syncthreads();
  #pragma unroll
  for (int off = 1; off < 256; off <<= 1){
    int t = (tid >= off) ? sd[tid - off] : 0;
    __syncthreads();
    sd[tid] += t;
    __syncthreads();
  }
  if (i < N_NODES) offs[i] = sd[tid] - v;
  if (tid == 255) bsum[blockIdx.x] = sd[255];
}

__global__ __launch_bounds__(256) void scan2_kernel(const int* __restrict__ bsum,
                                                    int* __restrict__ bbase, int nb){
  __shared__ int sd[256];
  const int tid = threadIdx.x;
  int v = (tid < nb) ? bsum[tid] : 0;
  sd[tid] = v; __syncthreads();
  #pragma unroll
  for (int off = 1; off < 256; off <<= 1){
    int t = (tid >= off) ? sd[tid - off] : 0;
    __syncthreads();
    sd[tid] += t;
    __syncthreads();
  }
  if (tid < nb) bbase[tid] = sd[tid] - v;
}

__global__ __launch_bounds__(256) void scan3_kernel(int* __restrict__ offs,
                                                    const int* __restrict__ bbase,
                                                    int* __restrict__ cur){
  const int i = blockIdx.x*256 + threadIdx.x;
  if (i < N_NODES){
    int o = offs[i] + bbase[blockIdx.x];
    offs[i] = o;
    cur[i] = o;
  }
  if (blockIdx.x == 0 && threadIdx.x == 0) offs[N_NODES] = E_TOT;
}

__global__ void scatter_kernel(const int* __restrict__ ei, int* __restrict__ cur,
                               int* __restrict__ ssrc){
  int e = blockIdx.x*blockDim.x + threadIdx.x;
  if (e >= E_TOT) return;
  int src, dst;
  if (e < N_EDGES){ src = ei[e]; dst = ei[N_EDGES + e]; }
  else            { src = e - N_EDGES; dst = src; }
  int pos = atomicAdd(&cur[dst], 1);
  ssrc[pos] = src;
}

// Deterministic bucket order: race-free in-register odd-even sort via shfl.
__global__ __launch_bounds__(256) void sort_kernel(const int* __restrict__ offs,
                                                   int* __restrict__ ssrc){
  const int wave = threadIdx.x >> 6, lane = threadIdx.x & 63;
  const int n = blockIdx.x*4 + wave;
  const int s0 = offs[n];
  const int len = offs[n+1] - s0;
  if (len <= 1) return;
  if (len <= 64){
    int v = (lane < len) ? ssrc[s0 + lane] : 0x7fffffff;
    for (int p = 0; p < len; ++p){
      const int left = ((lane & 1) == (p & 1));
      const int partner = left ? lane + 1 : lane - 1;
      const int pv = __shfl(v, partner & 63);
      const int nv = left ? min(v, pv) : max(v, pv);
      v = (partner >= 0 && partner < 64) ? nv : v;
    }
    if (lane < len) ssrc[s0 + lane] = v;
  } else if (lane == 0){
    for (int i = 1; i < len; ++i){
      int v = ssrc[s0 + i]; int j = i - 1;
      while (j >= 0 && ssrc[s0 + j] > v){ ssrc[s0 + j + 1] = ssrc[s0 + j]; --j; }
      ssrc[s0 + j + 1] = v;
    }
  }
}

// ---------------- prep: fp32 -> bf16 ----------------
__global__ __launch_bounds__(256) void cvt_x_kernel(const float* __restrict__ x,
                                                    ushort_t* __restrict__ xb){
  const int t = blockIdx.x*256 + threadIdx.x;
  const float4 a = ((const float4*)x)[t*2];
  const float4 b = ((const float4*)x)[t*2 + 1];
  uint4 o;
  o.x = (uint_t)f2b(a.x) | ((uint_t)f2b(a.y) << 16);
  o.y = (uint_t)f2b(a.z) | ((uint_t)f2b(a.w) << 16);
  o.z = (uint_t)f2b(b.x) | ((uint_t)f2b(b.y) << 16);
  o.w = (uint_t)f2b(b.z) | ((uint_t)f2b(b.w) << 16);
  ((uint4*)xb)[t] = o;
}

// W [K][N] fp32 -> Wt [N][K] bf16
__global__ __launch_bounds__(256) void transpose_bf16_kernel(const float* __restrict__ W,
                                                             ushort_t* __restrict__ Wt,
                                                             int K, int N){
  __shared__ float tile[64][65];
  const int k0 = blockIdx.x*64, n0 = blockIdx.y*64;
  const int c = threadIdx.x & 63, r4 = threadIdx.x >> 6;
  for (int r = r4; r < 64; r += 4)
    tile[r][c] = W[(size_t)(k0 + r)*N + n0 + c];
  __syncthreads();
  for (int r = r4; r < 64; r += 4)
    Wt[(size_t)(n0 + r)*K + k0 + c] = f2b(tile[c][r]);
}

// ---------------- bf16 MFMA GEMM + fused attention logits ----------------
// C[M, NH*CH] = A[M,K] @ Bt[NH*CH, K]^T ; logits for head = blockIdx.y.
// All fp32 epilogue math is explicit-fmaf-pinned for build-invariant numerics.
template<int K, int BM, int BN, int WR, int WC, int NH, int CH, bool CF32>
__global__ __launch_bounds__(256) void gemm_fused(const ushort_t* __restrict__ A,
                                                  const ushort_t* __restrict__ Bt,
                                                  void* __restrict__ Cout,
                                                  const float* __restrict__ a_src,
                                                  const float* __restrict__ a_dst,
                                                  float* __restrict__ als,
                                                  float* __restrict__ ald,
                                                  int M){
  constexpr int NTOT = NH*CH;
  __shared__ ushort_t As[BM*32];
  __shared__ ushort_t Bs[BN*32];
  __shared__ float slog[WC][BM][2];
  const int tid = threadIdx.x;
  const int wave = tid >> 6, lane = tid & 63, quad = lane >> 4, l16 = lane & 15;
  const int wm = wave % WR, wn = wave / WR;
  const int m0 = blockIdx.x*BM;
  const int head = blockIdx.y;
  const int n0 = head*BN;
  f32x4 acc[4][4] = {};
  for (int k0 = 0; k0 < K; k0 += 32){
    for (int idx = tid; idx < BM*4; idx += 256){
      int row = idx >> 2, ch = idx & 3;
      int gr = m0 + row; gr = (gr < M) ? gr : (M - 1);
      gld_lds16(A + (size_t)gr*K + k0 + ch*8, (char*)As + idx*16);
    }
    for (int idx = tid; idx < BN*4; idx += 256){
      int row = idx >> 2, ch = idx & 3;
      gld_lds16(Bt + (size_t)(n0 + row)*K + k0 + ch*8, (char*)Bs + idx*16);
    }
    __syncthreads();
    short8 af[4], bfr[4];
    #pragma unroll
    for (int i = 0; i < 4; ++i)
      af[i] = *(const short8*)(As + (wm*64 + i*16 + l16)*32 + quad*8);
    #pragma unroll
    for (int j = 0; j < 4; ++j)
      bfr[j] = *(const short8*)(Bs + (wn*64 + j*16 + l16)*32 + quad*8);
    #pragma unroll
    for (int i = 0; i < 4; ++i)
      #pragma unroll
      for (int j = 0; j < 4; ++j)
        acc[i][j] = __builtin_amdgcn_mfma_f32_16x16x32_bf16(af[i], bfr[j], acc[i][j], 0, 0, 0);
    __syncthreads();
  }
  // C store
  #pragma unroll
  for (int i = 0; i < 4; ++i){
    #pragma unroll
    for (int r = 0; r < 4; ++r){
      int row = m0 + wm*64 + i*16 + quad*4 + r;
      if (row < M){
        #pragma unroll
        for (int j = 0; j < 4; ++j){
          int col = n0 + wn*64 + j*16 + l16;
          if (CF32) ((float*)Cout)[(size_t)row*NTOT + col] = acc[i][j][r];
          else      ((ushort_t*)Cout)[(size_t)row*NTOT + col] = f2b(acc[i][j][r]);
        }
      }
    }
  }
  // fused logits (fmaf-pinned order)
  float aws[4], awd[4];
  #pragma unroll
  for (int j = 0; j < 4; ++j){
    int cih = wn*64 + j*16 + l16;
    aws[j] = a_src[head*CH + cih];
    awd[j] = a_dst[head*CH + cih];
  }
  #pragma unroll
  for (int i = 0; i < 4; ++i){
    #pragma unroll
    for (int r = 0; r < 4; ++r){
      float s = acc[i][0][r]*aws[0];
      s = fmaf(acc[i][1][r], aws[1], s);
      s = fmaf(acc[i][2][r], aws[2], s);
      s = fmaf(acc[i][3][r], aws[3], s);
      float d = acc[i][0][r]*awd[0];
      d = fmaf(acc[i][1][r], awd[1], d);
      d = fmaf(acc[i][2][r], awd[2], d);
      d = fmaf(acc[i][3][r], awd[3], d);
      #pragma unroll
      for (int off = 8; off >= 1; off >>= 1){
        s += __shfl_xor(s, off);
        d += __shfl_xor(d, off);
      }
      if (l16 == 0){
        slog[wn][wm*64 + i*16 + quad*4 + r][0] = s;
        slog[wn][wm*64 + i*16 + quad*4 + r][1] = d;
      }
    }
  }
  __syncthreads();
  for (int t = tid; t < BM; t += 256){
    float s = slog[0][t][0], d = slog[0][t][1];
    if (WC > 1){ s += slog[WC-1][t][0]; d += slog[WC-1][t][1]; }
    int row = m0 + t;
    if (row < M){
      als[row*NH + head] = s;
      ald[row*NH + head] = d;
    }
  }
}

#define FMA8(hv, al)                              \
  acc[0] = fmaf(blo((hv).x), (al), acc[0]);       \
  acc[1] = fmaf(bhi((hv).x), (al), acc[1]);       \
  acc[2] = fmaf(blo((hv).y), (al), acc[2]);       \
  acc[3] = fmaf(bhi((hv).y), (al), acc[3]);       \
  acc[4] = fmaf(blo((hv).z), (al), acc[4]);       \
  acc[5] = fmaf(bhi((hv).z), (al), acc[5]);       \
  acc[6] = fmaf(blo((hv).w), (al), acc[6]);       \
  acc[7] = fmaf(bhi((hv).w), (al), acc[7]);

// ---------------- layer-1 aggregation (wave per dst) ------------------------
__global__ __launch_bounds__(256) void agg1_kernel(const ushort_t* __restrict__ h1b,
                                                   const float* __restrict__ als,
                                                   const float* __restrict__ ald1,
                                                   const float* __restrict__ b1,
                                                   const int* __restrict__ offs,
                                                   const int* __restrict__ ssrc,
                                                   ushort_t* __restrict__ hb){
  __shared__ int   shsrc[4][64];
  __shared__ float shal[4][64][4];
  const int wave = threadIdx.x >> 6, lane = threadIdx.x & 63;
  const int n = blockIdx.x*4 + wave;
  const int head = lane >> 4;
  const float4 ald = ((const float4*)ald1)[n];
  const int s0 = offs[n], s1 = offs[n+1];

  // pass 1: softmax denominators; keep first-edge exp values in registers
  int   svc = 0;
  float sv0 = 0.f, sv1 = 0.f, sv2 = 0.f, sv3 = 0.f;
  float d0 = 0.f, d1 = 0.f, d2 = 0.f, d3 = 0.f;
  {
    const int e = s0 + lane;
    if (e < s1){
      svc = ssrc[e];
      const float4 as = ((const float4*)als)[svc];
      sv0 = __expf(lrelu(as.x + ald.x));
      sv1 = __expf(lrelu(as.y + ald.y));
      sv2 = __expf(lrelu(as.z + ald.z));
      sv3 = __expf(lrelu(as.w + ald.w));
      d0 = sv0; d1 = sv1; d2 = sv2; d3 = sv3;
    }
  }
  for (int e = s0 + lane + 64; e < s1; e += 64){
    const int sc = ssrc[e];
    const float4 as = ((const float4*)als)[sc];
    d0 += __expf(lrelu(as.x + ald.x));
    d1 += __expf(lrelu(as.y + ald.y));
    d2 += __expf(lrelu(as.z + ald.z));
    d3 += __expf(lrelu(as.w + ald.w));
  }
  #pragma unroll
  for (int off = 32; off >= 1; off >>= 1){
    d0 += __shfl_xor(d0, off);
    d1 += __shfl_xor(d1, off);
    d2 += __shfl_xor(d2, off);
    d3 += __shfl_xor(d3, off);
  }
  const float rd0 = 1.0f/(d0 + 1e-16f), rd1 = 1.0f/(d1 + 1e-16f);
  const float rd2 = 1.0f/(d2 + 1e-16f), rd3 = 1.0f/(d3 + 1e-16f);

  // pass 2: weighted aggregation; lane covers feats lane*8..+7 (head = lane>>4)
  float acc[8] = {0.f,0.f,0.f,0.f,0.f,0.f,0.f,0.f};
  for (int ce = s0; ce < s1; ce += 64){
    const int idx = ce + lane;
    if (idx < s1){
      int sc; float4 a4;
      if (ce == s0){
        sc = svc;                      // register reuse — no als re-gather
        a4.x = sv0 * rd0; a4.y = sv1 * rd1;
        a4.z = sv2 * rd2; a4.w = sv3 * rd3;
      } else {
        sc = ssrc[idx];
        const float4 as = ((const float4*)als)[sc];
        a4.x = __expf(lrelu(as.x + ald.x)) * rd0;
        a4.y = __expf(lrelu(as.y + ald.y)) * rd1;
        a4.z = __expf(lrelu(as.z + ald.z)) * rd2;
        a4.w = __expf(lrelu(as.w + ald.w)) * rd3;
      }
      shsrc[wave][lane] = sc;
      *(float4*)&shal[wave][lane][0] = a4;
    }
    __builtin_amdgcn_wave_barrier();      // stop compiler reordering LDS W->R
    const int nE = min(64, s1 - ce);
    for (int k = 0; k < nE; ++k){
      const int sA = shsrc[wave][k];
      const float aA = shal[wave][k][head];
      const uint4 hA = *(const uint4*)(h1b + (size_t)sA*F1 + lane*8);
      FMA8(hA, aA);
    }
    __builtin_amdgcn_wave_barrier();
  }
  const float4 ba = *(const float4*)(b1 + lane*8);
  const float4 bb = *(const float4*)(b1 + lane*8 + 4);
  float o0 = elu(acc[0] + ba.x), o1 = elu(acc[1] + ba.y);
  float o2 = elu(acc[2] + ba.z), o3 = elu(acc[3] + ba.w);
  float o4 = elu(acc[4] + bb.x), o5 = elu(acc[5] + bb.y);
  float o6 = elu(acc[6] + bb.z), o7 = elu(acc[7] + bb.w);
  uint4 o;
  o.x = (uint_t)f2b(o0) | ((uint_t)f2b(o1) << 16);
  o.y = (uint_t)f2b(o2) | ((uint_t)f2b(o3) << 16);
  o.z = (uint_t)f2b(o4) | ((uint_t)f2b(o5) << 16);
  o.w = (uint_t)f2b(o6) | ((uint_t)f2b(o7) << 16);
  *(uint4*)(hb + (size_t)n*F1 + lane*8) = o;
}

// ---------------- layer-2 aggregation (wave per dst, fp32 gather) ----------
__global__ __launch_bounds__(256) void agg2_kernel(const float* __restrict__ gb,
                                                   const float* __restrict__ als,
                                                   const float* __restrict__ ald2,
                                                   const float* __restrict__ b2,
                                                   const int* __restrict__ offs,
                                                   const int* __restrict__ ssrc,
                                                   float* __restrict__ out){
  __shared__ int   shsrc[4][64];
  __shared__ float shal[4][64];
  const int wave = threadIdx.x >> 6, lane = threadIdx.x & 63;
  const int n = blockIdx.x*4 + wave;
  const int g = lane >> 4, l16 = lane & 15;
  const float ald = ald2[n];
  const int s0 = offs[n], s1 = offs[n+1];

  float dsum = 0.f;
  for (int e = s0 + lane; e < s1; e += 64)
    dsum += __expf(lrelu(als[ssrc[e]] + ald));
  #pragma unroll
  for (int off = 32; off >= 1; off >>= 1)
    dsum += __shfl_xor(dsum, off);
  const float rd = 1.0f / (dsum + 1e-16f);

  float a0 = 0.f, a1 = 0.f, a2 = 0.f, a3 = 0.f;
  for (int ce = s0; ce < s1; ce += 64){
    const int idx = ce + lane;
    if (idx < s1){
      const int sc = ssrc[idx];
      shsrc[wave][lane] = sc;
      shal[wave][lane] = __expf(lrelu(als[sc] + ald)) * rd;
    }
    __builtin_amdgcn_wave_barrier();
    const int nE = min(64, s1 - ce);
    int k = 0;
    for (; k + 8 <= nE; k += 8){
      const int eA = k + g, eB = k + 4 + g;
      const int sA = shsrc[wave][eA], sB = shsrc[wave][eB];
      const float aA = shal[wave][eA], aB = shal[wave][eB];
      const float4 hA = *(const float4*)(gb + (size_t)sA*F_OUT + l16*4);
      const float4 hB = *(const float4*)(gb + (size_t)sB*F_OUT + l16*4);
      a0 = fmaf(hA.x, aA, a0); a1 = fmaf(hA.y, aA, a1);
      a2 = fmaf(hA.z, aA, a2); a3 = fmaf(hA.w, aA, a3);
      a0 = fmaf(hB.x, aB, a0); a1 = fmaf(hB.y, aB, a1);
      a2 = fmaf(hB.z, aB, a2); a3 = fmaf(hB.w, aB, a3);
    }
    for (; k < nE; k += 4){
      const int e = k + g;
      float al = 0.f;
      int sc = shsrc[wave][0];
      if (e < nE){ sc = shsrc[wave][e]; al = shal[wave][e]; }
      const float4 hv = *(const float4*)(gb + (size_t)sc*F_OUT + l16*4);
      a0 = fmaf(hv.x, al, a0); a1 = fmaf(hv.y, al, a1);
      a2 = fmaf(hv.z, al, a2); a3 = fmaf(hv.w, al, a3);
    }
    __builtin_amdgcn_wave_barrier();
  }
  a0 += __shfl_xor(a0, 16); a0 += __shfl_xor(a0, 32);
  a1 += __shfl_xor(a1, 16); a1 += __shfl_xor(a1, 32);
  a2 += __shfl_xor(a2, 16); a2 += __shfl_xor(a2, 32);
  a3 += __shfl_xor(a3, 16); a3 += __shfl_xor(a3, 32);
  if (g == 0){
    const float4 bv = *(const float4*)(b2 + l16*4);
    float4 o = {a0 + bv.x, a1 + bv.y, a2 + bv.z, a3 + bv.w};
    *(float4*)(out + (size_t)n*F_OUT + l16*4) = o;
  }
}

extern "C" void kernel_launch(void* const* d_in, const int* in_sizes, int n_in,
                              void* d_out, int out_size, void* d_ws, size_t ws_size,
                              hipStream_t stream){
  const float* x      = (const float*)d_in[0];
  const int*   ei     = (const int*)  d_in[1];
  const float* W1     = (const float*)d_in[2];
  const float* a_src1 = (const float*)d_in[3];
  const float* a_dst1 = (const float*)d_in[4];
  const float* b1     = (const float*)d_in[5];
  const float* W2     = (const float*)d_in[6];
  const float* a_src2 = (const float*)d_in[7];
  const float* a_dst2 = (const float*)d_in[8];
  const float* b2     = (const float*)d_in[9];
  float* out = (float*)d_out;

  char* ws = (char*)d_ws;
  ushort_t* xb   = (ushort_t*)(ws + 0UL);            // [N,256] bf16 = 25.6 MB
  ushort_t* h1b  = (ushort_t*)(ws + 25600000UL);     // [N,512] bf16 = 51.2 MB
  ushort_t* hb   = (ushort_t*)(ws + 76800000UL);     // [N,512] bf16 = 51.2 MB
  float*    gb   = (float*)   (ws + 128000000UL);    // [N,64] fp32 = 12.8 MB
  ushort_t* W1t  = (ushort_t*)(ws + 140800000UL);    // [512][256] bf16
  ushort_t* W2t  = (ushort_t*)(ws + 141062144UL);    // [64][512] bf16
  float*    als1 = (float*)   (ws + 141127680UL);    // [N,4]
  float*    ald1 = (float*)   (ws + 141927680UL);    // [N,4]
  float*    als2 = (float*)   (ws + 142727680UL);    // [N]
  float*    ald2 = (float*)   (ws + 142927680UL);    // [N]
  int*      deg  = (int*)     (ws + 143127680UL);    // [N]
  int*      offs = (int*)     (ws + 143327680UL);    // [N+1]
  int*      bsum = (int*)     (ws + 143527744UL);    // [196]
  int*      bbase= (int*)     (ws + 143528768UL);    // [196]
  int*      cur  = (int*)     (ws + 143529792UL);    // [N]
  int*      ssrc = (int*)     (ws + 143729792UL);    // [E_TOT]

  hipMemsetAsync(deg, 0, 200000, stream);

  const int eb = (E_TOT + 255) / 256;
  const int nb = (N_NODES + 255) / 256;              // 196
  hist_kernel   <<<eb, 256, 0, stream>>>(ei, deg);
  scan1_kernel  <<<nb, 256, 0, stream>>>(deg, offs, bsum);
  scan2_kernel  <<<1, 256, 0, stream>>>(bsum, bbase, nb);
  scan3_kernel  <<<nb, 256, 0, stream>>>(offs, bbase, cur);
  scatter_kernel<<<eb, 256, 0, stream>>>(ei, cur, ssrc);
  sort_kernel   <<<12500, 256, 0, stream>>>(offs, ssrc);   // deterministic order

  cvt_x_kernel         <<<6250, 256, 0, stream>>>(x, xb);
  transpose_bf16_kernel<<<dim3(4, 8), 256, 0, stream>>>(W1, W1t, F_IN, F1);
  transpose_bf16_kernel<<<dim3(8, 1), 256, 0, stream>>>(W2, W2t, F1, F_OUT);

  // layer 1: bf16 gemm + fused logits; grid.y = head
  gemm_fused<F_IN, 128, 128, 2, 2, 4, 128, false>
    <<<dim3(391, 4), 256, 0, stream>>>(xb, W1t, h1b,
                                       a_src1, a_dst1, als1, ald1, N_NODES);
  agg1_kernel<<<12500, 256, 0, stream>>>(h1b, als1, ald1, b1, offs, ssrc, hb);

  // layer 2: bf16 gemm + fused logits (1 head), fp32 C
  gemm_fused<F1, 256, 64, 4, 1, 1, 64, true>
    <<<dim3(196, 1), 256, 0, stream>>>(hb, W2t, gb,
                                       a_src2, a_dst2, als2, ald2, N_NODES);
  agg2_kernel<<<12500, 256, 0, stream>>>(gb, als2, ald2, b2, offs, ssrc, out);
}